// Round 1
// baseline (75.765 us; speedup 1.0000x reference)
//
#include <hip/hip_runtime.h>
#include <math.h>

// Net: 4 layers of out = 0.8*(x@W^T) + 0.2*max_i(W[o,i]*x[b,i]) + b
// B=1024, dims 256 -> 512 -> 512 -> 512 -> 1. All fp32, VALU-bound.

#define B_TOT 1024

// ---------------------------------------------------------------------------
// Tiled layer kernel: 32x32 block tile, 2x2 micro-tile, BK=32.
// LDS tiles stored k-major [k][row] with stride 34:
//  - staging ds_write pattern -> <=2-way bank aliasing (free)
//  - float2 fragment reads stay 8B-aligned and conflict-free/broadcast
// ---------------------------------------------------------------------------
__global__ __launch_bounds__(256) void layer_tile(
    const float* __restrict__ X,    // B x K
    const float* __restrict__ Wm,   // O x K
    const float* __restrict__ bias, // O
    float* __restrict__ Y,          // B x O
    int K, int O)
{
    __shared__ float Xs[32][34];    // [k][b_local]
    __shared__ float Ws[32][34];    // [k][o_local]

    const int t  = threadIdx.x;
    const int tx = t & 15;          // o dimension (0..15)
    const int ty = t >> 4;          // b dimension (0..15)

    const int bx = blockIdx.x;      // o tile (0..15)
    const int by = blockIdx.y;      // b tile (0..31)

    // staging coords: each thread loads one float4 per tile per K-iter
    const int sr = t >> 3;          // row within tile (0..31)
    const int sc = (t & 7) * 4;     // k offset within tile (0,4,...,28)

    const float* xrow = X + (size_t)(by * 32 + sr) * K;
    const float* wrow = Wm + (size_t)(bx * 32 + sr) * K;

    float s00 = 0.f, s01 = 0.f, s10 = 0.f, s11 = 0.f;
    float m00 = -INFINITY, m01 = -INFINITY, m10 = -INFINITY, m11 = -INFINITY;

    for (int k0 = 0; k0 < K; k0 += 32) {
        float4 xv = *(const float4*)&xrow[k0 + sc];
        float4 wv = *(const float4*)&wrow[k0 + sc];
        __syncthreads();
        Xs[sc + 0][sr] = xv.x;
        Xs[sc + 1][sr] = xv.y;
        Xs[sc + 2][sr] = xv.z;
        Xs[sc + 3][sr] = xv.w;
        Ws[sc + 0][sr] = wv.x;
        Ws[sc + 1][sr] = wv.y;
        Ws[sc + 2][sr] = wv.z;
        Ws[sc + 3][sr] = wv.w;
        __syncthreads();

        #pragma unroll
        for (int kk = 0; kk < 32; ++kk) {
            float2 xf = *(const float2*)&Xs[kk][2 * ty];
            float2 wf = *(const float2*)&Ws[kk][2 * tx];
            float p00 = wf.x * xf.x; s00 += p00; m00 = fmaxf(m00, p00);
            float p01 = wf.y * xf.x; s01 += p01; m01 = fmaxf(m01, p01);
            float p10 = wf.x * xf.y; s10 += p10; m10 = fmaxf(m10, p10);
            float p11 = wf.y * xf.y; s11 += p11; m11 = fmaxf(m11, p11);
        }
    }

    const int ob = bx * 32 + 2 * tx;
    const int bb = by * 32 + 2 * ty;
    const float bias0 = bias[ob];
    const float bias1 = bias[ob + 1];

    Y[(size_t)bb * O + ob]           = 0.8f * s00 + 0.2f * m00 + bias0;
    Y[(size_t)bb * O + ob + 1]       = 0.8f * s01 + 0.2f * m01 + bias1;
    Y[(size_t)(bb + 1) * O + ob]     = 0.8f * s10 + 0.2f * m10 + bias0;
    Y[(size_t)(bb + 1) * O + ob + 1] = 0.8f * s11 + 0.2f * m11 + bias1;
}

// ---------------------------------------------------------------------------
// Final layer: O=1. One wave per batch row, wave shuffle reduction.
// ---------------------------------------------------------------------------
__global__ __launch_bounds__(256) void layer4_kernel(
    const float* __restrict__ H,    // 1024 x 512
    const float* __restrict__ W4,   // 512
    const float* __restrict__ b4,   // 1
    float* __restrict__ out)        // 1024
{
    const int wave = threadIdx.x >> 6;
    const int lane = threadIdx.x & 63;
    const int b = blockIdx.x * 4 + wave;

    const float* h = H + (size_t)b * 512;

    float s = 0.f;
    float m = -INFINITY;
    #pragma unroll
    for (int i = 0; i < 2; ++i) {
        const int k = lane * 4 + i * 256;
        float4 hv = *(const float4*)&h[k];
        float4 wv = *(const float4*)&W4[k];
        float p0 = hv.x * wv.x;
        float p1 = hv.y * wv.y;
        float p2 = hv.z * wv.z;
        float p3 = hv.w * wv.w;
        s += p0 + p1 + p2 + p3;
        m = fmaxf(m, fmaxf(fmaxf(p0, p1), fmaxf(p2, p3)));
    }

    #pragma unroll
    for (int off = 32; off; off >>= 1) {
        s += __shfl_xor(s, off, 64);
        m = fmaxf(m, __shfl_xor(m, off, 64));
    }

    if (lane == 0) {
        out[b] = 0.8f * s + 0.2f * m + b4[0];
    }
}

extern "C" void kernel_launch(void* const* d_in, const int* in_sizes, int n_in,
                              void* d_out, int out_size, void* d_ws, size_t ws_size,
                              hipStream_t stream)
{
    const float* x  = (const float*)d_in[0];
    const float* W1 = (const float*)d_in[1];
    const float* b1 = (const float*)d_in[2];
    const float* W2 = (const float*)d_in[3];
    const float* b2 = (const float*)d_in[4];
    const float* W3 = (const float*)d_in[5];
    const float* b3 = (const float*)d_in[6];
    const float* W4 = (const float*)d_in[7];
    const float* b4 = (const float*)d_in[8];

    float* h1 = (float*)d_ws;                    // 1024x512
    float* h2 = h1 + (size_t)B_TOT * 512;        // 1024x512
    float* h3 = h1;                              // reuse h1's buffer (dead after layer 2)

    dim3 grid(16, 32);  // 512/32 o-tiles, 1024/32 b-tiles

    layer_tile<<<grid, 256, 0, stream>>>(x,  W1, b1, h1, 256, 512);
    layer_tile<<<grid, 256, 0, stream>>>(h1, W2, b2, h2, 512, 512);
    layer_tile<<<grid, 256, 0, stream>>>(h2, W3, b3, h3, 512, 512);
    layer4_kernel<<<256, 256, 0, stream>>>(h3, W4, b4, (float*)d_out);
}

// Round 2
// 74.036 us; speedup vs baseline: 1.0234x; 1.0234x over previous
//
#include <hip/hip_runtime.h>
#include <math.h>

// Net: 4 layers of out = 0.8*(x@W^T) + 0.2*max_i(W[o,i]*x[b,i]) + b
// B=1024, dims 256 -> 512 -> 512 -> 512 -> 1. All fp32, VALU-bound.
//
// Structure: split-K=2 per layer (grid 1024 blocks -> 4 waves/SIMD), partial
// (sum, max) written per split; the combine (0.8*(s0+s1)+0.2*max(m0,m1)+bias)
// is fused into the NEXT layer's staging read. Register-prefetch
// double-buffered LDS staging hides global latency under the 32-step
// VALU inner loop.

#define B_TOT 1024
#define SP (B_TOT * 512)   // per-split partial stride (floats)

// Fused input read: either plain X (layer 1) or combine of previous layer's
// split partials + previous bias.
template<bool COMBINE>
__device__ __forceinline__ float4 load_x4(
    const float* __restrict__ X0,
    const float* __restrict__ Ps0, const float* __restrict__ Ps1,
    const float* __restrict__ Pm0, const float* __restrict__ Pm1,
    const float* __restrict__ pb,
    int row, int K, int k)
{
    if constexpr (!COMBINE) {
        return *(const float4*)&X0[(size_t)row * K + k];
    } else {
        const size_t off = (size_t)row * K + k;
        float4 s0 = *(const float4*)&Ps0[off];
        float4 s1 = *(const float4*)&Ps1[off];
        float4 m0 = *(const float4*)&Pm0[off];
        float4 m1 = *(const float4*)&Pm1[off];
        float4 bb = *(const float4*)&pb[k];
        float4 h;
        h.x = fmaf(0.2f, fmaxf(m0.x, m1.x), fmaf(0.8f, s0.x + s1.x, bb.x));
        h.y = fmaf(0.2f, fmaxf(m0.y, m1.y), fmaf(0.8f, s0.y + s1.y, bb.y));
        h.z = fmaf(0.2f, fmaxf(m0.z, m1.z), fmaf(0.8f, s0.z + s1.z, bb.z));
        h.w = fmaf(0.2f, fmaxf(m0.w, m1.w), fmaf(0.8f, s0.w + s1.w, bb.w));
        return h;
    }
}

// 32x32 block tile, 2x2 micro-tile, BK=32, split-K via blockIdx.z.
// LDS tiles k-major [k][row] stride 34: staging writes <=2-way bank alias
// (free), float2 fragment reads 8B-aligned, conflict-free/broadcast.
template<bool COMBINE>
__global__ __launch_bounds__(256, 4) void layer_split(
    const float* __restrict__ X0,
    const float* __restrict__ Ps0, const float* __restrict__ Ps1,
    const float* __restrict__ Pm0, const float* __restrict__ Pm1,
    const float* __restrict__ pb,
    const float* __restrict__ Wm,     // O x K
    float* __restrict__ PSout,        // [split][B][O] partial sums
    float* __restrict__ PMout,        // [split][B][O] partial maxes
    int K, int O, int KS)             // KS = K per split
{
    __shared__ float Xs[32][34];      // [k][b_local]
    __shared__ float Ws[32][34];      // [k][o_local]

    const int t  = threadIdx.x;
    const int tx = t & 15;            // o (0..15)
    const int ty = t >> 4;            // b (0..15)

    const int bx = blockIdx.x;        // o tile
    const int by = blockIdx.y;        // b tile
    const int bz = blockIdx.z;        // split

    const int sr = t >> 3;            // staging row (0..31)
    const int sc = (t & 7) * 4;       // staging k offset (0,4,...,28)

    const int xrow  = by * 32 + sr;
    const int kbase = bz * KS;

    const float* wrow = Wm + (size_t)(bx * 32 + sr) * K + kbase;

    // prefetch tile 0
    float4 xv = load_x4<COMBINE>(X0, Ps0, Ps1, Pm0, Pm1, pb, xrow, K, kbase + sc);
    float4 wv = *(const float4*)&wrow[sc];

    float s00 = 0.f, s01 = 0.f, s10 = 0.f, s11 = 0.f;
    float m00 = -INFINITY, m01 = -INFINITY, m10 = -INFINITY, m11 = -INFINITY;

    for (int k0 = 0; k0 < KS; k0 += 32) {
        __syncthreads();              // previous tile fully consumed
        Xs[sc + 0][sr] = xv.x;
        Xs[sc + 1][sr] = xv.y;
        Xs[sc + 2][sr] = xv.z;
        Xs[sc + 3][sr] = xv.w;
        Ws[sc + 0][sr] = wv.x;
        Ws[sc + 1][sr] = wv.y;
        Ws[sc + 2][sr] = wv.z;
        Ws[sc + 3][sr] = wv.w;

        // prefetch next tile (latency hides under the compute below)
        if (k0 + 32 < KS) {
            xv = load_x4<COMBINE>(X0, Ps0, Ps1, Pm0, Pm1, pb,
                                  xrow, K, kbase + k0 + 32 + sc);
            wv = *(const float4*)&wrow[k0 + 32 + sc];
        }
        __syncthreads();              // writes visible

        #pragma unroll
        for (int kk = 0; kk < 32; ++kk) {
            float2 xf = *(const float2*)&Xs[kk][2 * ty];
            float2 wf = *(const float2*)&Ws[kk][2 * tx];
            float p00 = wf.x * xf.x; s00 += p00; m00 = fmaxf(m00, p00);
            float p01 = wf.y * xf.x; s01 += p01; m01 = fmaxf(m01, p01);
            float p10 = wf.x * xf.y; s10 += p10; m10 = fmaxf(m10, p10);
            float p11 = wf.y * xf.y; s11 += p11; m11 = fmaxf(m11, p11);
        }
    }

    const int ob = bx * 32 + 2 * tx;
    const int bb = by * 32 + 2 * ty;
    float* So = PSout + (size_t)bz * SP;
    float* Mo = PMout + (size_t)bz * SP;

    So[(size_t)bb * O + ob]           = s00;
    So[(size_t)bb * O + ob + 1]       = s01;
    So[(size_t)(bb + 1) * O + ob]     = s10;
    So[(size_t)(bb + 1) * O + ob + 1] = s11;
    Mo[(size_t)bb * O + ob]           = m00;
    Mo[(size_t)bb * O + ob + 1]       = m01;
    Mo[(size_t)(bb + 1) * O + ob]     = m10;
    Mo[(size_t)(bb + 1) * O + ob + 1] = m11;
}

// Final layer: O=1. One wave per batch row; combines layer-3 split partials
// on the fly; wave shuffle reduction.
__global__ __launch_bounds__(256) void layer4_split(
    const float* __restrict__ Ps0, const float* __restrict__ Ps1,
    const float* __restrict__ Pm0, const float* __restrict__ Pm1,
    const float* __restrict__ pb,    // b3
    const float* __restrict__ W4,    // 512
    const float* __restrict__ b4,    // 1
    float* __restrict__ out)         // 1024
{
    const int wave = threadIdx.x >> 6;
    const int lane = threadIdx.x & 63;
    const int b = blockIdx.x * 4 + wave;

    const size_t base = (size_t)b * 512;

    float s = 0.f;
    float m = -INFINITY;
    #pragma unroll
    for (int i = 0; i < 2; ++i) {
        const int k = i * 256 + lane * 4;
        float4 s0 = *(const float4*)&Ps0[base + k];
        float4 s1 = *(const float4*)&Ps1[base + k];
        float4 m0 = *(const float4*)&Pm0[base + k];
        float4 m1 = *(const float4*)&Pm1[base + k];
        float4 bb = *(const float4*)&pb[k];
        float4 wv = *(const float4*)&W4[k];
        float4 h;
        h.x = fmaf(0.2f, fmaxf(m0.x, m1.x), fmaf(0.8f, s0.x + s1.x, bb.x));
        h.y = fmaf(0.2f, fmaxf(m0.y, m1.y), fmaf(0.8f, s0.y + s1.y, bb.y));
        h.z = fmaf(0.2f, fmaxf(m0.z, m1.z), fmaf(0.8f, s0.z + s1.z, bb.z));
        h.w = fmaf(0.2f, fmaxf(m0.w, m1.w), fmaf(0.8f, s0.w + s1.w, bb.w));
        float p0 = h.x * wv.x;
        float p1 = h.y * wv.y;
        float p2 = h.z * wv.z;
        float p3 = h.w * wv.w;
        s += p0 + p1 + p2 + p3;
        m = fmaxf(m, fmaxf(fmaxf(p0, p1), fmaxf(p2, p3)));
    }

    #pragma unroll
    for (int off = 32; off; off >>= 1) {
        s += __shfl_xor(s, off, 64);
        m = fmaxf(m, __shfl_xor(m, off, 64));
    }

    if (lane == 0) {
        out[b] = 0.8f * s + 0.2f * m + b4[0];
    }
}

extern "C" void kernel_launch(void* const* d_in, const int* in_sizes, int n_in,
                              void* d_out, int out_size, void* d_ws, size_t ws_size,
                              hipStream_t stream)
{
    const float* x  = (const float*)d_in[0];
    const float* W1 = (const float*)d_in[1];
    const float* b1 = (const float*)d_in[2];
    const float* W2 = (const float*)d_in[3];
    const float* b2 = (const float*)d_in[4];
    const float* W3 = (const float*)d_in[5];
    const float* b3 = (const float*)d_in[6];
    const float* W4 = (const float*)d_in[7];
    const float* b4 = (const float*)d_in[8];

    float* ws = (float*)d_ws;
    // Layer1 partials: [0, 4*SP). Layer2 partials: [4*SP, 8*SP).
    // Layer3 partials reuse layer1's region (dead by then). 16 MB total.
    float* P1s = ws;
    float* P1m = ws + 2 * (size_t)SP;
    float* P2s = ws + 4 * (size_t)SP;
    float* P2m = ws + 6 * (size_t)SP;
    float* P3s = P1s;
    float* P3m = P1m;

    dim3 grid(16, 32, 2);   // o-tiles, b-tiles, splits

    layer_split<false><<<grid, 256, 0, stream>>>(
        x, nullptr, nullptr, nullptr, nullptr, nullptr,
        W1, P1s, P1m, 256, 512, 128);

    layer_split<true><<<grid, 256, 0, stream>>>(
        nullptr, P1s, P1s + SP, P1m, P1m + SP, b1,
        W2, P2s, P2m, 512, 512, 256);

    layer_split<true><<<grid, 256, 0, stream>>>(
        nullptr, P2s, P2s + SP, P2m, P2m + SP, b2,
        W3, P3s, P3m, 512, 512, 256);

    layer4_split<<<256, 256, 0, stream>>>(
        P3s, P3s + SP, P3m, P3m + SP, b3, W4, b4, (float*)d_out);
}

// Round 3
// 73.738 us; speedup vs baseline: 1.0275x; 1.0040x over previous
//
#include <hip/hip_runtime.h>
#include <math.h>

// Net: 4 layers of out = 0.8*(x@W^T) + 0.2*max_i(W[o,i]*x[b,i]) + b
// B=1024, dims 256 -> 512 -> 512 -> 512 -> 1. All fp32, VALU-bound.
//
// R3: no split-K (R2's combine-in-consumer was L2-BW-bound: 20B/element
// staging re-read by 16 o-tiles). Each layer writes finished h directly.
// 64x32 tile, 2x2 microtile, 512-thread blocks (grid 256 = 1 block/CU),
// double-buffered LDS with register prefetch and ONE barrier per K-tile.

__global__ __launch_bounds__(512, 2) void layer_fused(
    const float* __restrict__ X,    // B x K
    const float* __restrict__ Wm,   // O x K
    const float* __restrict__ bias, // O
    float* __restrict__ Y,          // B x O
    int K, int O)
{
    // k-major LDS tiles; strides 66/34 keep float2 reads 8B-aligned and
    // make both staging writes and fragment reads <=2-way bank aliased.
    __shared__ float Xs[2][32][66];   // [buf][k][b_local]  16.9 KB
    __shared__ float Ws[2][32][34];   // [buf][k][o_local]   8.7 KB

    const int t  = threadIdx.x;
    const int tx = t & 15;            // o-pair (0..15)
    const int ty = t >> 4;            // b-pair (0..31)

    const int bx = blockIdx.x;        // o tile (O/32)
    const int by = blockIdx.y;        // b tile (B/64)

    // staging coords: X one float4/thread (64 rows x 32 k),
    //                 W one float2/thread (32 rows x 32 k)
    const int xr = t >> 3;            // 0..63
    const int xc = (t & 7) * 4;       // 0,4,...,28
    const int wr = t >> 4;            // 0..31
    const int wc = (t & 15) * 2;      // 0,2,...,30

    const float* xrow = X + (size_t)(by * 64 + xr) * K + xc;
    const float* wrow = Wm + (size_t)(bx * 32 + wr) * K + wc;

    const int T = K >> 5;

    // stage tile 0
    float4 xv = *(const float4*)xrow;
    float2 wv = *(const float2*)wrow;
    Xs[0][xc + 0][xr] = xv.x;
    Xs[0][xc + 1][xr] = xv.y;
    Xs[0][xc + 2][xr] = xv.z;
    Xs[0][xc + 3][xr] = xv.w;
    Ws[0][wc + 0][wr] = wv.x;
    Ws[0][wc + 1][wr] = wv.y;
    __syncthreads();

    float s00 = 0.f, s01 = 0.f, s10 = 0.f, s11 = 0.f;
    float m00 = -INFINITY, m01 = -INFINITY, m10 = -INFINITY, m11 = -INFINITY;

    for (int tt = 0; tt < T; ++tt) {
        const int cur = tt & 1;

        // prefetch next tile into registers (hides under compute below)
        if (tt + 1 < T) {
            xv = *(const float4*)(xrow + (tt + 1) * 32);
            wv = *(const float2*)(wrow + (tt + 1) * 32);
        }

        #pragma unroll
        for (int kk = 0; kk < 32; ++kk) {
            float2 xf = *(const float2*)&Xs[cur][kk][2 * ty];
            float2 wf = *(const float2*)&Ws[cur][kk][2 * tx];
            float p00 = wf.x * xf.x; s00 += p00; m00 = fmaxf(m00, p00);
            float p01 = wf.y * xf.x; s01 += p01; m01 = fmaxf(m01, p01);
            float p10 = wf.x * xf.y; s10 += p10; m10 = fmaxf(m10, p10);
            float p11 = wf.y * xf.y; s11 += p11; m11 = fmaxf(m11, p11);
        }

        // write next tile into the other buffer; the single barrier below
        // (a) publishes these writes for the next iteration and
        // (b) keeps any wave from overwriting a buffer still being read.
        if (tt + 1 < T) {
            const int nxt = cur ^ 1;
            Xs[nxt][xc + 0][xr] = xv.x;
            Xs[nxt][xc + 1][xr] = xv.y;
            Xs[nxt][xc + 2][xr] = xv.z;
            Xs[nxt][xc + 3][xr] = xv.w;
            Ws[nxt][wc + 0][wr] = wv.x;
            Ws[nxt][wc + 1][wr] = wv.y;
            __syncthreads();
        }
    }

    const int ob = bx * 32 + 2 * tx;
    const int bb = by * 64 + 2 * ty;
    const float2 bv = *(const float2*)&bias[ob];

    float2 r0, r1;
    r0.x = fmaf(0.2f, m00, fmaf(0.8f, s00, bv.x));
    r0.y = fmaf(0.2f, m01, fmaf(0.8f, s01, bv.y));
    r1.x = fmaf(0.2f, m10, fmaf(0.8f, s10, bv.x));
    r1.y = fmaf(0.2f, m11, fmaf(0.8f, s11, bv.y));

    *(float2*)&Y[(size_t)bb * O + ob]       = r0;
    *(float2*)&Y[(size_t)(bb + 1) * O + ob] = r1;
}

// Final layer: O=1. One wave per batch row, wave shuffle reduction.
__global__ __launch_bounds__(256) void layer4_kernel(
    const float* __restrict__ H,    // 1024 x 512 (finished h3)
    const float* __restrict__ W4,   // 512
    const float* __restrict__ b4,   // 1
    float* __restrict__ out)        // 1024
{
    const int wave = threadIdx.x >> 6;
    const int lane = threadIdx.x & 63;
    const int b = blockIdx.x * 4 + wave;

    const float* h = H + (size_t)b * 512;

    float s = 0.f;
    float m = -INFINITY;
    #pragma unroll
    for (int i = 0; i < 2; ++i) {
        const int k = i * 256 + lane * 4;
        float4 hv = *(const float4*)&h[k];
        float4 wv = *(const float4*)&W4[k];
        float p0 = hv.x * wv.x;
        float p1 = hv.y * wv.y;
        float p2 = hv.z * wv.z;
        float p3 = hv.w * wv.w;
        s += p0 + p1 + p2 + p3;
        m = fmaxf(m, fmaxf(fmaxf(p0, p1), fmaxf(p2, p3)));
    }

    #pragma unroll
    for (int off = 32; off; off >>= 1) {
        s += __shfl_xor(s, off, 64);
        m = fmaxf(m, __shfl_xor(m, off, 64));
    }

    if (lane == 0) {
        out[b] = 0.8f * s + 0.2f * m + b4[0];
    }
}

extern "C" void kernel_launch(void* const* d_in, const int* in_sizes, int n_in,
                              void* d_out, int out_size, void* d_ws, size_t ws_size,
                              hipStream_t stream)
{
    const float* x  = (const float*)d_in[0];
    const float* W1 = (const float*)d_in[1];
    const float* b1 = (const float*)d_in[2];
    const float* W2 = (const float*)d_in[3];
    const float* b2 = (const float*)d_in[4];
    const float* W3 = (const float*)d_in[5];
    const float* b3 = (const float*)d_in[6];
    const float* W4 = (const float*)d_in[7];
    const float* b4 = (const float*)d_in[8];

    float* h1 = (float*)d_ws;                    // 1024x512 finished h
    float* h2 = h1 + (size_t)1024 * 512;
    float* h3 = h1;                              // reuse (dead after layer 2)

    dim3 grid(16, 16);  // O/32 = 16 o-tiles, B/64 = 16 b-tiles (256 blocks)

    layer_fused<<<grid, 512, 0, stream>>>(x,  W1, b1, h1, 256, 512);
    layer_fused<<<grid, 512, 0, stream>>>(h1, W2, b2, h2, 512, 512);
    layer_fused<<<grid, 512, 0, stream>>>(h2, W3, b3, h3, 512, 512);
    layer4_kernel<<<256, 256, 0, stream>>>(h3, W4, b4, (float*)d_out);
}